// Round 3
// baseline (163.449 us; speedup 1.0000x reference)
//
#include <hip/hip_runtime.h>

#define NB 32
#define NS 2048
#define NE 8
// softmax scale 1/sqrt(d_k)=0.5 folded with log2(e) so we can use v_exp_f32 (2^x)
#define QSCALE 0.72134752044448170367f

// ---------------------------------------------------------------------------
// Kernel A: per (b, q-chunk, k-slice) partial attention, register-blocked.
//   h = cos(x + theta); scores bounded in [-2,2] -> no max pass needed.
//   Each thread owns QPT query rows (both heads) and accumulates
//   sum(exp(s)*v) + sum(exp(s)) over its k-slice. One LDS k-row read is
//   reused for QPT queries. KSLICE small (128) -> many blocks -> high
//   occupancy to hide exp/LDS latency.
// FUSED=true (single slice) normalizes + projects + writes out directly.
// ---------------------------------------------------------------------------
template <int KSLICE, int QPT, bool FUSED>
__global__ __launch_bounds__(256, 8) void attn_part_kernel(
    const float* __restrict__ x, const float* __restrict__ theta,
    const float* __restrict__ Wout, float* __restrict__ outp) {
  // +1 pad row so the software-pipelined prefetch can read one row past the
  // end unconditionally (values discarded). Skip pad when it would push a
  // 64 KB config over the LDS limit (fused path keeps the guard instead).
  constexpr int PAD = (KSLICE < 2048) ? 8 : 0;
  __shared__ float kv[KSLICE * 8 + PAD];

  const int b = blockIdx.z;
  const int slice = blockIdx.y;
  const int qbase = blockIdx.x * (256 * QPT) + threadIdx.x;  // +256*g per query
  const int k0 = slice * KSLICE;

  float th[8];
#pragma unroll
  for (int e = 0; e < 8; ++e) th[e] = theta[e];

  // Stage the k-slice of h into LDS (computed on the fly from x).
  for (int r = threadIdx.x; r < KSLICE; r += 256) {
    const float4* xr = (const float4*)(x + ((size_t)b * NS + k0 + r) * 8);
    float4 lo = xr[0], hi = xr[1];
    lo.x = __cosf(lo.x + th[0]);
    lo.y = __cosf(lo.y + th[1]);
    lo.z = __cosf(lo.z + th[2]);
    lo.w = __cosf(lo.w + th[3]);
    hi.x = __cosf(hi.x + th[4]);
    hi.y = __cosf(hi.y + th[5]);
    hi.z = __cosf(hi.z + th[6]);
    hi.w = __cosf(hi.w + th[7]);
    ((float4*)kv)[2 * r] = lo;
    ((float4*)kv)[2 * r + 1] = hi;
  }

  // This thread's QPT query rows, pre-scaled by 0.5*log2(e).
  float4 qlo[QPT], qhi[QPT];
#pragma unroll
  for (int g = 0; g < QPT; ++g) {
    const float4* xq = (const float4*)(x + ((size_t)b * NS + qbase + 256 * g) * 8);
    float4 lo = xq[0], hi = xq[1];
    lo.x = __cosf(lo.x + th[0]) * QSCALE;
    lo.y = __cosf(lo.y + th[1]) * QSCALE;
    lo.z = __cosf(lo.z + th[2]) * QSCALE;
    lo.w = __cosf(lo.w + th[3]) * QSCALE;
    hi.x = __cosf(hi.x + th[4]) * QSCALE;
    hi.y = __cosf(hi.y + th[5]) * QSCALE;
    hi.z = __cosf(hi.z + th[6]) * QSCALE;
    hi.w = __cosf(hi.w + th[7]) * QSCALE;
    qlo[g] = lo;
    qhi[g] = hi;
  }

  __syncthreads();

  float4 a0[QPT], a1[QPT];
  float d0[QPT], d1[QPT];
#pragma unroll
  for (int g = 0; g < QPT; ++g) {
    a0[g] = make_float4(0.f, 0.f, 0.f, 0.f);
    a1[g] = make_float4(0.f, 0.f, 0.f, 0.f);
    d0[g] = 0.f;
    d1[g] = 0.f;
  }

  const float4* kp = (const float4*)kv;
  // Software-pipelined: prefetch row j+1 (unconditional; pad row absorbs the
  // overrun) while computing row j.
  float4 kl = kp[0], kh = kp[1];
#pragma unroll 8
  for (int j = 0; j < KSLICE; ++j) {
    float4 nl, nh;
    if (!FUSED || j + 1 < KSLICE) {
      nl = kp[2 * j + 2];  // broadcast read, conflict-free
      nh = kp[2 * j + 3];
    }
#pragma unroll
    for (int g = 0; g < QPT; ++g) {
      float s0 = qlo[g].x * kl.x + qlo[g].y * kl.y + qlo[g].z * kl.z + qlo[g].w * kl.w;
      float s1 = qhi[g].x * kh.x + qhi[g].y * kh.y + qhi[g].z * kh.z + qhi[g].w * kh.w;
      float p0 = __builtin_amdgcn_exp2f(s0);  // v_exp_f32
      float p1 = __builtin_amdgcn_exp2f(s1);
      a0[g].x += p0 * kl.x;
      a0[g].y += p0 * kl.y;
      a0[g].z += p0 * kl.z;
      a0[g].w += p0 * kl.w;
      d0[g] += p0;
      a1[g].x += p1 * kh.x;
      a1[g].y += p1 * kh.y;
      a1[g].z += p1 * kh.z;
      a1[g].w += p1 * kh.w;
      d1[g] += p1;
    }
    kl = nl;
    kh = nh;
  }

#pragma unroll
  for (int g = 0; g < QPT; ++g) {
    const int q = qbase + 256 * g;
    if (FUSED) {
      const float i0 = 1.0f / d0[g], i1 = 1.0f / d1[g];
      float m[8] = {a0[g].x * i0, a0[g].y * i0, a0[g].z * i0, a0[g].w * i0,
                    a1[g].x * i1, a1[g].y * i1, a1[g].z * i1, a1[g].w * i1};
      float o[8];
#pragma unroll
      for (int e = 0; e < 8; ++e) {
        float s = 0.f;
#pragma unroll
        for (int f = 0; f < 8; ++f) s += m[f] * Wout[e * 8 + f];
        o[e] = s;
      }
      float4* op = (float4*)(outp + ((size_t)b * NS + q) * 8);
      op[0] = make_float4(o[0], o[1], o[2], o[3]);
      op[1] = make_float4(o[4], o[5], o[6], o[7]);
    } else {
      // partial layout: [slice][component(10)][B*S]  (coalesced stores)
      const int idx = b * NS + q;
      float* p = outp + (size_t)slice * 10 * (NB * NS) + idx;
      p[0 * (NB * NS)] = a0[g].x;
      p[1 * (NB * NS)] = a0[g].y;
      p[2 * (NB * NS)] = a0[g].z;
      p[3 * (NB * NS)] = a0[g].w;
      p[4 * (NB * NS)] = a1[g].x;
      p[5 * (NB * NS)] = a1[g].y;
      p[6 * (NB * NS)] = a1[g].z;
      p[7 * (NB * NS)] = a1[g].w;
      p[8 * (NB * NS)] = d0[g];
      p[9 * (NB * NS)] = d1[g];
    }
  }
}

// ---------------------------------------------------------------------------
// Kernel B: sum slice partials, normalize, apply W_out^T, write out.
// ---------------------------------------------------------------------------
__global__ __launch_bounds__(256) void attn_reduce_kernel(
    const float* __restrict__ part, const float* __restrict__ Wout,
    float* __restrict__ out, int nslice) {
  const int idx = blockIdx.x * 256 + threadIdx.x;  // 0 .. B*S-1
  float a[10];
#pragma unroll
  for (int c = 0; c < 10; ++c) a[c] = 0.f;
  for (int sl = 0; sl < nslice; ++sl) {
    const float* p = part + (size_t)sl * 10 * (NB * NS) + idx;
#pragma unroll
    for (int c = 0; c < 10; ++c) a[c] += p[c * (NB * NS)];
  }
  const float i0 = 1.0f / a[8], i1 = 1.0f / a[9];
  float m[8] = {a[0] * i0, a[1] * i0, a[2] * i0, a[3] * i0,
                a[4] * i1, a[5] * i1, a[6] * i1, a[7] * i1};
  float o[8];
#pragma unroll
  for (int e = 0; e < 8; ++e) {
    float s = 0.f;
#pragma unroll
    for (int f = 0; f < 8; ++f) s += m[f] * Wout[e * 8 + f];
    o[e] = s;
  }
  float4* op = (float4*)(out + (size_t)idx * 8);
  op[0] = make_float4(o[0], o[1], o[2], o[3]);
  op[1] = make_float4(o[4], o[5], o[6], o[7]);
}

extern "C" void kernel_launch(void* const* d_in, const int* in_sizes, int n_in,
                              void* d_out, int out_size, void* d_ws,
                              size_t ws_size, hipStream_t stream) {
  const float* x = (const float*)d_in[0];      // [32, 2048, 8]
  const float* theta = (const float*)d_in[1];  // [8]
  const float* W = (const float*)d_in[2];      // [8, 8]
  float* out = (float*)d_out;                  // [32, 2048, 8]
  float* ws = (float*)d_ws;

  const size_t per_slice = (size_t)NB * NS * 10 * sizeof(float);  // 2.62 MB

  if (ws_size >= 16 * per_slice) {
    // 16-way split-K, 2 queries/thread: 2048 blocks = 8/CU, 32 waves/CU.
    attn_part_kernel<128, 2, false>
        <<<dim3(NS / 512, 16, NB), 256, 0, stream>>>(x, theta, W, ws);
    attn_reduce_kernel<<<(NB * NS) / 256, 256, 0, stream>>>(ws, W, out, 16);
  } else if (ws_size >= 8 * per_slice) {
    // 8-way split-K, 2 queries/thread: 1024 blocks = 4/CU, 16 waves/CU.
    attn_part_kernel<256, 2, false>
        <<<dim3(NS / 512, 8, NB), 256, 0, stream>>>(x, theta, W, ws);
    attn_reduce_kernel<<<(NB * NS) / 256, 256, 0, stream>>>(ws, W, out, 8);
  } else if (ws_size >= 4 * per_slice) {
    attn_part_kernel<512, 2, false>
        <<<dim3(NS / 512, 4, NB), 256, 0, stream>>>(x, theta, W, ws);
    attn_reduce_kernel<<<(NB * NS) / 256, 256, 0, stream>>>(ws, W, out, 4);
  } else {
    // Fused single-pass fallback (64 KB LDS, no workspace needed).
    attn_part_kernel<2048, 2, true>
        <<<dim3(NS / 512, 1, NB), 256, 0, stream>>>(x, theta, W, out);
  }
}

// Round 5
// 132.023 us; speedup vs baseline: 1.2380x; 1.2380x over previous
//
#include <hip/hip_runtime.h>

#define NB 32
#define NS 2048
#define NE 8
// softmax scale 1/sqrt(d_k)=0.5 folded with log2(e) so we can use v_exp_f32 (2^x)
#define QSCALE 0.72134752044448170367f

typedef float v2f __attribute__((ext_vector_type(2)));
typedef float v4f __attribute__((ext_vector_type(4)));

// Packed f32 math via native vector ops -> LLVM selects v_pk_{mul,fma,add}_f32
// on gfx90a+ with correct op_sel/op_sel_hi (no hand-asm modifier footguns).
__device__ __forceinline__ v2f pkfma(v2f a, v2f b, v2f c) {
  return __builtin_elementwise_fma(a, b, c);
}

// ---------------------------------------------------------------------------
// Kernel A: per (b, q-chunk, k-slice) partial attention, packed-f32 math.
//   h = cos(x + theta); scores bounded in [-2,2] -> no max pass needed.
//   LDS stores each k-row HEAD-INTERLEAVED: (k0,k4),(k1,k5),(k2,k6),(k3,k7)
//   so head0/head1 run in the lo/hi halves of v_pk_* instructions:
//   per (q,k,both heads): 4 pk (dot) + 2 exp + 4 pk_fma + 1 pk_add = 11 slots
//   (vs ~20 scalar). One LDS row read is reused for QPT queries.
// FUSED=true (single slice) normalizes + projects + writes out directly.
// ---------------------------------------------------------------------------
template <int KSLICE, int QPT, bool FUSED>
__global__ __launch_bounds__(256) void attn_part_kernel(
    const float* __restrict__ x, const float* __restrict__ theta,
    const float* __restrict__ Wout, float* __restrict__ outp) {
  __shared__ float kv[KSLICE * 8];

  const int b = blockIdx.z;
  const int slice = blockIdx.y;
  const int qbase = blockIdx.x * (256 * QPT) + threadIdx.x;  // +256*g per query
  const int k0 = slice * KSLICE;

  float th[8];
#pragma unroll
  for (int e = 0; e < 8; ++e) th[e] = theta[e];

  // Stage the k-slice of h into LDS, head-interleaved per row.
  for (int r = threadIdx.x; r < KSLICE; r += 256) {
    const float4* xr = (const float4*)(x + ((size_t)b * NS + k0 + r) * 8);
    float4 lo = xr[0], hi = xr[1];
    lo.x = __cosf(lo.x + th[0]);
    lo.y = __cosf(lo.y + th[1]);
    lo.z = __cosf(lo.z + th[2]);
    lo.w = __cosf(lo.w + th[3]);
    hi.x = __cosf(hi.x + th[4]);
    hi.y = __cosf(hi.y + th[5]);
    hi.z = __cosf(hi.z + th[6]);
    hi.w = __cosf(hi.w + th[7]);
    // interleave: (k0,k4,k1,k5) (k2,k6,k3,k7)
    ((float4*)kv)[2 * r] = make_float4(lo.x, hi.x, lo.y, hi.y);
    ((float4*)kv)[2 * r + 1] = make_float4(lo.z, hi.z, lo.w, hi.w);
  }

  // This thread's QPT query rows as head-interleaved pairs, pre-scaled.
  v2f qp[QPT][4];
#pragma unroll
  for (int g = 0; g < QPT; ++g) {
    const float4* xq = (const float4*)(x + ((size_t)b * NS + qbase + 256 * g) * 8);
    float4 lo = xq[0], hi = xq[1];
    qp[g][0] = (v2f){__cosf(lo.x + th[0]) * QSCALE, __cosf(hi.x + th[4]) * QSCALE};
    qp[g][1] = (v2f){__cosf(lo.y + th[1]) * QSCALE, __cosf(hi.y + th[5]) * QSCALE};
    qp[g][2] = (v2f){__cosf(lo.z + th[2]) * QSCALE, __cosf(hi.z + th[6]) * QSCALE};
    qp[g][3] = (v2f){__cosf(lo.w + th[3]) * QSCALE, __cosf(hi.w + th[7]) * QSCALE};
  }

  __syncthreads();

  v2f acc[QPT][4];  // acc[g][i] = (sum p0*k_i, sum p1*k_{4+i})
  v2f den[QPT];     // (sum p0, sum p1)
#pragma unroll
  for (int g = 0; g < QPT; ++g) {
    acc[g][0] = (v2f){0.f, 0.f};
    acc[g][1] = (v2f){0.f, 0.f};
    acc[g][2] = (v2f){0.f, 0.f};
    acc[g][3] = (v2f){0.f, 0.f};
    den[g] = (v2f){0.f, 0.f};
  }

  const v4f* kp = (const v4f*)kv;
#pragma unroll 4
  for (int j = 0; j < KSLICE; ++j) {
    // Broadcast LDS reads (all lanes same row) -> conflict-free b128 x2.
    v4f A = kp[2 * j];
    v4f Bv = kp[2 * j + 1];
    v2f kk0 = A.xy;   // (k0, k4)
    v2f kk1 = A.zw;   // (k1, k5)
    v2f kk2 = Bv.xy;  // (k2, k6)
    v2f kk3 = Bv.zw;  // (k3, k7)
#pragma unroll
    for (int g = 0; g < QPT; ++g) {
      v2f s = qp[g][0] * kk0;
      s = pkfma(qp[g][1], kk1, s);
      s = pkfma(qp[g][2], kk2, s);
      s = pkfma(qp[g][3], kk3, s);
      v2f P;
      P.x = __builtin_amdgcn_exp2f(s.x);  // v_exp_f32
      P.y = __builtin_amdgcn_exp2f(s.y);
      acc[g][0] = pkfma(P, kk0, acc[g][0]);
      acc[g][1] = pkfma(P, kk1, acc[g][1]);
      acc[g][2] = pkfma(P, kk2, acc[g][2]);
      acc[g][3] = pkfma(P, kk3, acc[g][3]);
      den[g] = den[g] + P;
    }
  }

#pragma unroll
  for (int g = 0; g < QPT; ++g) {
    const int q = qbase + 256 * g;
    if (FUSED) {
      const float i0 = 1.0f / den[g].x, i1 = 1.0f / den[g].y;
      float m[8] = {acc[g][0].x * i0, acc[g][1].x * i0, acc[g][2].x * i0,
                    acc[g][3].x * i0, acc[g][0].y * i1, acc[g][1].y * i1,
                    acc[g][2].y * i1, acc[g][3].y * i1};
      float o[8];
#pragma unroll
      for (int e = 0; e < 8; ++e) {
        float s = 0.f;
#pragma unroll
        for (int f = 0; f < 8; ++f) s += m[f] * Wout[e * 8 + f];
        o[e] = s;
      }
      float4* op = (float4*)(outp + ((size_t)b * NS + q) * 8);
      op[0] = make_float4(o[0], o[1], o[2], o[3]);
      op[1] = make_float4(o[4], o[5], o[6], o[7]);
    } else {
      // partial layout: [slice][component(10)][B*S]  (coalesced stores)
      const int idx = b * NS + q;
      float* p = outp + (size_t)slice * 10 * (NB * NS) + idx;
      p[0 * (NB * NS)] = acc[g][0].x;
      p[1 * (NB * NS)] = acc[g][1].x;
      p[2 * (NB * NS)] = acc[g][2].x;
      p[3 * (NB * NS)] = acc[g][3].x;
      p[4 * (NB * NS)] = acc[g][0].y;
      p[5 * (NB * NS)] = acc[g][1].y;
      p[6 * (NB * NS)] = acc[g][2].y;
      p[7 * (NB * NS)] = acc[g][3].y;
      p[8 * (NB * NS)] = den[g].x;
      p[9 * (NB * NS)] = den[g].y;
    }
  }
}

// ---------------------------------------------------------------------------
// Kernel B: sum slice partials, normalize, apply W_out^T, write out.
// ---------------------------------------------------------------------------
__global__ __launch_bounds__(256) void attn_reduce_kernel(
    const float* __restrict__ part, const float* __restrict__ Wout,
    float* __restrict__ out, int nslice) {
  const int idx = blockIdx.x * 256 + threadIdx.x;  // 0 .. B*S-1
  float a[10];
#pragma unroll
  for (int c = 0; c < 10; ++c) a[c] = 0.f;
  for (int sl = 0; sl < nslice; ++sl) {
    const float* p = part + (size_t)sl * 10 * (NB * NS) + idx;
#pragma unroll
    for (int c = 0; c < 10; ++c) a[c] += p[c * (NB * NS)];
  }
  const float i0 = 1.0f / a[8], i1 = 1.0f / a[9];
  float m[8] = {a[0] * i0, a[1] * i0, a[2] * i0, a[3] * i0,
                a[4] * i1, a[5] * i1, a[6] * i1, a[7] * i1};
  float o[8];
#pragma unroll
  for (int e = 0; e < 8; ++e) {
    float s = 0.f;
#pragma unroll
    for (int f = 0; f < 8; ++f) s += m[f] * Wout[e * 8 + f];
    o[e] = s;
  }
  float4* op = (float4*)(out + (size_t)idx * 8);
  op[0] = make_float4(o[0], o[1], o[2], o[3]);
  op[1] = make_float4(o[4], o[5], o[6], o[7]);
}

extern "C" void kernel_launch(void* const* d_in, const int* in_sizes, int n_in,
                              void* d_out, int out_size, void* d_ws,
                              size_t ws_size, hipStream_t stream) {
  const float* x = (const float*)d_in[0];      // [32, 2048, 8]
  const float* theta = (const float*)d_in[1];  // [8]
  const float* W = (const float*)d_in[2];      // [8, 8]
  float* out = (float*)d_out;                  // [32, 2048, 8]
  float* ws = (float*)d_ws;

  const size_t per_slice = (size_t)NB * NS * 10 * sizeof(float);  // 2.62 MB

  if (ws_size >= 8 * per_slice) {
    // 8-way split-K, 2 queries/thread: 1024 blocks = 4/CU, 16 waves/CU.
    attn_part_kernel<256, 2, false>
        <<<dim3(NS / 512, 8, NB), 256, 0, stream>>>(x, theta, W, ws);
    attn_reduce_kernel<<<(NB * NS) / 256, 256, 0, stream>>>(ws, W, out, 8);
  } else if (ws_size >= 4 * per_slice) {
    attn_part_kernel<512, 2, false>
        <<<dim3(NS / 512, 4, NB), 256, 0, stream>>>(x, theta, W, ws);
    attn_reduce_kernel<<<(NB * NS) / 256, 256, 0, stream>>>(ws, W, out, 4);
  } else if (ws_size >= 2 * per_slice) {
    attn_part_kernel<1024, 2, false>
        <<<dim3(NS / 512, 2, NB), 256, 0, stream>>>(x, theta, W, ws);
    attn_reduce_kernel<<<(NB * NS) / 256, 256, 0, stream>>>(ws, W, out, 2);
  } else {
    // Fused single-pass fallback (64 KB LDS, no workspace needed).
    attn_part_kernel<2048, 2, true>
        <<<dim3(NS / 512, 1, NB), 256, 0, stream>>>(x, theta, W, out);
  }
}